// Round 12
// baseline (798.826 us; speedup 1.0000x reference)
//
#include <hip/hip_runtime.h>
#include <hip/hip_bf16.h>
#include <math.h>

#define N_NODES 100000
#define N_EDGES 1600000
#define N_FEAT 75
#define HID 64
#define NUM_GRAPHS 4096
#define BN_EPS 1e-5f
#define NSLICE 64

#define NBIN 400          // bins of 250 nodes
#define NPB 250
#define BCAP 4800
#define BIN_BLOCKS 256
#define BIN_CHUNK ((N_EDGES + BIN_BLOCKS - 1) / BIN_BLOCKS)   // 6250

#define XPAD 68           // LDS row stride (words): 16B-aligned, bank-shift 4

typedef short bf16x8 __attribute__((ext_vector_type(8)));
typedef float f32x4 __attribute__((ext_vector_type(4)));

// ---------------- bf16 helpers ----------------

__device__ __forceinline__ unsigned bf2_pack(float a, float b) {
  unsigned ua = __float_as_uint(a); ua += 0x7FFF + ((ua >> 16) & 1);
  unsigned ub = __float_as_uint(b); ub += 0x7FFF + ((ub >> 16) & 1);
  return (ua >> 16) | (ub & 0xFFFF0000u);
}
__device__ __forceinline__ unsigned short bf1_pack(float a) {
  unsigned ua = __float_as_uint(a); ua += 0x7FFF + ((ua >> 16) & 1);
  return (unsigned short)(ua >> 16);
}
__device__ __forceinline__ float4 bf4_unpack(uint2 u) {
  return make_float4(__uint_as_float(u.x << 16), __uint_as_float(u.x & 0xFFFF0000u),
                     __uint_as_float(u.y << 16), __uint_as_float(u.y & 0xFFFF0000u));
}
__device__ __forceinline__ float bf1_unpack(unsigned short u) {
  return __uint_as_float((unsigned)u << 16);
}

// ---------------- setup: LDS-binned counting sort (no per-edge global atomics) ---------

__global__ __launch_bounds__(256) void bin_kernel(const int* __restrict__ src,
                                                  const int* __restrict__ dst,
                                                  int* __restrict__ binCur,
                                                  unsigned* __restrict__ staging) {
  __shared__ unsigned ent[BIN_CHUNK];
  __shared__ short binv[BIN_CHUNK];
  __shared__ int lcnt[NBIN];
  __shared__ int lbase[NBIN];
  int t = threadIdx.x;
  int c0 = blockIdx.x * BIN_CHUNK;
  int c1 = min(c0 + BIN_CHUNK, N_EDGES);
  int n = c1 - c0;
  for (int i = t; i < NBIN; i += 256) lcnt[i] = 0;
  __syncthreads();
  for (int i = t; i < n; i += 256) {
    int d = dst[c0 + i];
    int s = src[c0 + i];
    int b = d / NPB;
    int ld = d - b * NPB;
    ent[i] = ((unsigned)ld << 17) | (unsigned)s;
    binv[i] = (short)b;
    atomicAdd(&lcnt[b], 1);
  }
  __syncthreads();
  for (int i = t; i < NBIN; i += 256)
    lbase[i] = atomicAdd(&binCur[i], lcnt[i]);
  __syncthreads();
  for (int i = t; i < n; i += 256) {
    int b = binv[i];
    int slot = atomicAdd(&lbase[b], 1);
    if (slot < BCAP) staging[(size_t)b * BCAP + slot] = ent[i];
  }
}

__global__ __launch_bounds__(256) void binscan_kernel(const int* __restrict__ binCur,
                                                      int* __restrict__ binBase,
                                                      int* __restrict__ rowptr) {
  __shared__ int ls[256];
  int t = threadIdx.x;
  int v0 = (2 * t < NBIN) ? binCur[2 * t] : 0;
  int v1 = (2 * t + 1 < NBIN) ? binCur[2 * t + 1] : 0;
  ls[t] = v0 + v1;
  __syncthreads();
  for (int off = 1; off < 256; off <<= 1) {
    int a = (t >= off) ? ls[t - off] : 0;
    __syncthreads();
    ls[t] += a;
    __syncthreads();
  }
  int run = (t > 0) ? ls[t - 1] : 0;
  if (2 * t < NBIN) binBase[2 * t] = run;
  if (2 * t + 1 < NBIN) binBase[2 * t + 1] = run + v0;
  if (t == 0) rowptr[N_NODES] = N_EDGES;
}

__global__ __launch_bounds__(256) void sort_kernel(const unsigned* __restrict__ staging,
                                                   const int* __restrict__ binCur,
                                                   const int* __restrict__ binBase,
                                                   float* __restrict__ dinv,
                                                   int* __restrict__ rowptr,
                                                   int* __restrict__ csr) {
  __shared__ unsigned in[BCAP];
  __shared__ int outw[BCAP];
  __shared__ int cnt[NPB];
  __shared__ int scanb[256];
  int b = blockIdx.x, t = threadIdx.x;
  int n = min(binCur[b], BCAP);
  int base = binBase[b];
  const unsigned* st = staging + (size_t)b * BCAP;
  for (int i = t; i < NPB; i += 256) cnt[i] = 0;
  __syncthreads();
  for (int i = t; i < n; i += 256) {
    unsigned e = st[i];
    in[i] = e;
    atomicAdd(&cnt[e >> 17], 1);
  }
  __syncthreads();
  int c = (t < NPB) ? cnt[t] : 0;
  scanb[t] = c;
  __syncthreads();
  for (int off = 1; off < 256; off <<= 1) {
    int a = (t >= off) ? scanb[t - off] : 0;
    __syncthreads();
    scanb[t] += a;
    __syncthreads();
  }
  int excl = scanb[t] - c;
  if (t < NPB) {
    int v = b * NPB + t;
    dinv[v] = rsqrtf((float)c + 1.0f);
    rowptr[v] = base + excl;
    cnt[t] = excl;
  }
  __syncthreads();
  for (int i = t; i < n; i += 256) {
    unsigned e = in[i];
    int p = atomicAdd(&cnt[e >> 17], 1);
    outw[p] = (int)(e & 0x1FFFFu);
  }
  __syncthreads();
  for (int i = t; i < n; i += 256) csr[base + i] = outw[i];
}

// S[v] = dv*(dv + sum of dinv[src])
__global__ void ssum_kernel(const int* __restrict__ csr, const int* __restrict__ rowptr,
                            const float* __restrict__ dinv, float* __restrict__ Ssum) {
  int v = blockIdx.x * blockDim.x + threadIdx.x;
  if (v >= N_NODES) return;
  float dv = dinv[v];
  float s = dv;
  int e = rowptr[v], e1 = rowptr[v + 1];
  for (; e + 4 <= e1; e += 4) {
    float a = dinv[csr[e]], b2 = dinv[csr[e + 1]];
    float c2 = dinv[csr[e + 2]], d2 = dinv[csr[e + 3]];
    s += (a + b2) + (c2 + d2);
  }
  for (; e < e1; ++e) s += dinv[csr[e]];
  Ssum[v] = dv * s;
}

// ---------------- GEMM layer 1: fp32 X [N,75] @ W -> bf16 Hs (VALU) ----------------

__global__ __launch_bounds__(256) void gemm1_kernel(
    const float* __restrict__ X, const float* __restrict__ W,
    const float* __restrict__ dinv, unsigned short* __restrict__ Hout) {
  __shared__ float xs[N_FEAT][XPAD];   // [k][row]
  __shared__ float ws[N_FEAT][64];     // [k][col]
  int t = threadIdx.x;
  int rowBase = blockIdx.x * 64;
  for (int i = t; i < N_FEAT * 64; i += 256) ws[i >> 6][i & 63] = W[i];
  if (rowBase + 64 <= N_NODES) {
    const float* Xb = X + (size_t)rowBase * N_FEAT;
    for (int i = t; i < 64 * N_FEAT; i += 256) {
      int r = i / N_FEAT, k = i - r * N_FEAT;
      xs[k][r] = Xb[i];
    }
  } else {
    for (int i = t; i < 64 * N_FEAT; i += 256) {
      int r = i / N_FEAT, k = i - r * N_FEAT;
      int row = rowBase + r;
      xs[k][r] = (row < N_NODES) ? X[(size_t)row * N_FEAT + k] : 0.f;
    }
  }
  __syncthreads();
  int ty = t >> 4, tx = t & 15;
  int r0 = ty * 4, c0 = tx * 4;
  float acc[4][4] = {};
  for (int k = 0; k < N_FEAT; ++k) {
    float4 a = *(const float4*)&xs[k][r0];
    float4 bq = *(const float4*)&ws[k][c0];
    float av[4] = {a.x, a.y, a.z, a.w};
    float bv[4] = {bq.x, bq.y, bq.z, bq.w};
    #pragma unroll
    for (int i = 0; i < 4; ++i)
      #pragma unroll
      for (int j = 0; j < 4; ++j)
        acc[i][j] = fmaf(av[i], bv[j], acc[i][j]);
  }
  #pragma unroll
  for (int i = 0; i < 4; ++i) {
    int row = rowBase + r0 + i;
    if (row < N_NODES) {
      float dv = dinv[row];
      uint2 packed = make_uint2(bf2_pack(acc[i][0] * dv, acc[i][1] * dv),
                                bf2_pack(acc[i][2] * dv, acc[i][3] * dv));
      *(uint2*)&Hout[(size_t)row * HID + c0] = packed;
    }
  }
}

// ---------------- GEMM layers 2-4 (MFMA): bf16 Z [N,64] @ bf16 Wsw -> bf16 Hs ---------

__global__ __launch_bounds__(256) void gemmB_kernel(
    const unsigned short* __restrict__ Zin, const unsigned short* __restrict__ Wsw,
    const float* __restrict__ dinv, unsigned short* __restrict__ Hout) {
  __shared__ float ldsC[64][XPAD];
  int t = threadIdx.x;
  int w = t >> 6, lane = t & 63;
  int quad = lane >> 4, li = lane & 15;
  int row0 = blockIdx.x * 64;
  int rowA = row0 + w * 16 + li;
  if (rowA >= N_NODES) rowA = N_NODES - 1;
  const bf16x8* Zr = (const bf16x8*)(Zin + (size_t)rowA * HID + quad * 8);
  bf16x8 a0 = Zr[0];               // kc=0: k = quad*8 + j
  bf16x8 a1 = Zr[4];               // kc=1: +32 shorts
  const bf16x8* Wr = (const bf16x8*)Wsw;
  f32x4 accs[4];
  #pragma unroll
  for (int nt = 0; nt < 4; ++nt) {
    bf16x8 b0 = Wr[(nt * 2 + 0) * 64 + lane];
    bf16x8 b1 = Wr[(nt * 2 + 1) * 64 + lane];
    f32x4 acc = {0.f, 0.f, 0.f, 0.f};
    acc = __builtin_amdgcn_mfma_f32_16x16x32_bf16(a0, b0, acc, 0, 0, 0);
    acc = __builtin_amdgcn_mfma_f32_16x16x32_bf16(a1, b1, acc, 0, 0, 0);
    accs[nt] = acc;
  }
  float dv[4];
  #pragma unroll
  for (int r = 0; r < 4; ++r) {
    int rr = row0 + w * 16 + quad * 4 + r;
    dv[r] = dinv[min(rr, N_NODES - 1)];
  }
  #pragma unroll
  for (int nt = 0; nt < 4; ++nt)
    #pragma unroll
    for (int r = 0; r < 4; ++r)
      ldsC[w * 16 + quad * 4 + r][nt * 16 + li] = accs[nt][r] * dv[r];
  __syncthreads();
  int rl = t >> 2, c0 = (t & 3) * 16;
  int row = row0 + rl;
  if (row < N_NODES) {
    unsigned p[8];
    #pragma unroll
    for (int j = 0; j < 8; ++j)
      p[j] = bf2_pack(ldsC[rl][c0 + 2 * j], ldsC[rl][c0 + 2 * j + 1]);
    uint4* dst0 = (uint4*)(Hout + (size_t)row * HID + c0);
    dst0[0] = make_uint4(p[0], p[1], p[2], p[3]);
    dst0[1] = make_uint4(p[4], p[5], p[6], p[7]);
  }
}

// ---------------- aggregation + relu + BN-stats + fused BN-fold epilogue ----------------
// Dual-node interleave: each quad processes its two nodes' edge chunks together
// (~32 outstanding loads/wave). Last block to finish folds BN (alpha/beta/ab/Wsw/cv).

#define AGG_WAVES 4

__global__ __launch_bounds__(256) void agg_kernel(
    const unsigned short* __restrict__ Hs, const int* __restrict__ csr,
    const int* __restrict__ rowptr, const float* __restrict__ S,
    const float* __restrict__ dinv, const float* __restrict__ cvec,
    const float* __restrict__ bias, unsigned short* __restrict__ Z,
    float* __restrict__ stats, int* __restrict__ layerDone,
    const float* __restrict__ g, const float* __restrict__ be,
    const float* __restrict__ Wnext, unsigned short* __restrict__ Wsw,
    float* __restrict__ cvecOut, float* __restrict__ ab, int hasNext) {
  int t = threadIdx.x;
  int wave = t >> 6, lane = t & 63;
  int q = lane >> 4, li = lane & 15;
  int f = li * 4;
  int nodeBase = blockIdx.x * (AGG_WAVES * 8) + wave * 8 + q;
  float4 cl = *(const float4*)&cvec[f];
  float4 bl = *(const float4*)&bias[f];
  float4 ssum = make_float4(0.f, 0.f, 0.f, 0.f);
  float4 ssq  = make_float4(0.f, 0.f, 0.f, 0.f);

  int vA = nodeBase, vB = nodeBase + 4;
  bool okA = vA < N_NODES, okB = vB < N_NODES;
  int vAc = okA ? vA : N_NODES - 1;
  int vBc = okB ? vB : N_NODES - 1;
  float4 accA = bf4_unpack(*(const uint2*)&Hs[(size_t)vAc * HID + f]);
  float4 accB = bf4_unpack(*(const uint2*)&Hs[(size_t)vBc * HID + f]);
  int eA = okA ? rowptr[vA] : 0, e1A = okA ? rowptr[vA + 1] : 0;
  int eB = okB ? rowptr[vB] : 0, e1B = okB ? rowptr[vB + 1] : 0;
  int lastA = max(e1A - 1, 0), lastB = max(e1B - 1, 0);
  while (eA < e1A || eB < e1B) {
    int eiA[8], eiB[8];
    #pragma unroll
    for (int k2 = 0; k2 < 8; ++k2) eiA[k2] = csr[min(eA + k2, lastA)];
    #pragma unroll
    for (int k2 = 0; k2 < 8; ++k2) eiB[k2] = csr[min(eB + k2, lastB)];
    uint2 uA[8], uB[8];
    #pragma unroll
    for (int k2 = 0; k2 < 8; ++k2) uA[k2] = *(const uint2*)&Hs[(size_t)eiA[k2] * HID + f];
    #pragma unroll
    for (int k2 = 0; k2 < 8; ++k2) uB[k2] = *(const uint2*)&Hs[(size_t)eiB[k2] * HID + f];
    #pragma unroll
    for (int k2 = 0; k2 < 8; ++k2) {
      float4 h = bf4_unpack(uA[k2]);
      float mk = (eA + k2 < e1A) ? 1.f : 0.f;
      accA.x = fmaf(mk, h.x, accA.x);
      accA.y = fmaf(mk, h.y, accA.y);
      accA.z = fmaf(mk, h.z, accA.z);
      accA.w = fmaf(mk, h.w, accA.w);
    }
    #pragma unroll
    for (int k2 = 0; k2 < 8; ++k2) {
      float4 h = bf4_unpack(uB[k2]);
      float mk = (eB + k2 < e1B) ? 1.f : 0.f;
      accB.x = fmaf(mk, h.x, accB.x);
      accB.y = fmaf(mk, h.y, accB.y);
      accB.z = fmaf(mk, h.z, accB.z);
      accB.w = fmaf(mk, h.w, accB.w);
    }
    eA = min(eA + 8, e1A);
    eB = min(eB + 8, e1B);
  }
  if (okA) {
    float dv = dinv[vA], sv = S[vA];
    float4 z;
    z.x = fmaxf(fmaf(dv, accA.x, fmaf(sv, cl.x, bl.x)), 0.f);
    z.y = fmaxf(fmaf(dv, accA.y, fmaf(sv, cl.y, bl.y)), 0.f);
    z.z = fmaxf(fmaf(dv, accA.z, fmaf(sv, cl.z, bl.z)), 0.f);
    z.w = fmaxf(fmaf(dv, accA.w, fmaf(sv, cl.w, bl.w)), 0.f);
    *(uint2*)&Z[(size_t)vA * HID + f] = make_uint2(bf2_pack(z.x, z.y), bf2_pack(z.z, z.w));
    ssum.x += z.x; ssum.y += z.y; ssum.z += z.z; ssum.w += z.w;
    ssq.x += z.x * z.x; ssq.y += z.y * z.y; ssq.z += z.z * z.z; ssq.w += z.w * z.w;
  }
  if (okB) {
    float dv = dinv[vB], sv = S[vB];
    float4 z;
    z.x = fmaxf(fmaf(dv, accB.x, fmaf(sv, cl.x, bl.x)), 0.f);
    z.y = fmaxf(fmaf(dv, accB.y, fmaf(sv, cl.y, bl.y)), 0.f);
    z.z = fmaxf(fmaf(dv, accB.z, fmaf(sv, cl.z, bl.z)), 0.f);
    z.w = fmaxf(fmaf(dv, accB.w, fmaf(sv, cl.w, bl.w)), 0.f);
    *(uint2*)&Z[(size_t)vB * HID + f] = make_uint2(bf2_pack(z.x, z.y), bf2_pack(z.z, z.w));
    ssum.x += z.x; ssum.y += z.y; ssum.z += z.z; ssum.w += z.w;
    ssq.x += z.x * z.x; ssq.y += z.y * z.y; ssq.z += z.z * z.z; ssq.w += z.w * z.w;
  }
  #pragma unroll
  for (int m = 16; m <= 32; m <<= 1) {
    ssum.x += __shfl_xor(ssum.x, m); ssum.y += __shfl_xor(ssum.y, m);
    ssum.z += __shfl_xor(ssum.z, m); ssum.w += __shfl_xor(ssum.w, m);
    ssq.x  += __shfl_xor(ssq.x,  m); ssq.y  += __shfl_xor(ssq.y,  m);
    ssq.z  += __shfl_xor(ssq.z,  m); ssq.w  += __shfl_xor(ssq.w,  m);
  }
  __shared__ float redS[AGG_WAVES][64];
  __shared__ float redQ[AGG_WAVES][64];
  if (q == 0) {
    *(float4*)&redS[wave][f] = ssum;
    *(float4*)&redQ[wave][f] = ssq;
  }
  __syncthreads();
  if (wave == 0) {
    float s = 0.f, qq = 0.f;
    #pragma unroll
    for (int i = 0; i < AGG_WAVES; ++i) { s += redS[i][lane]; qq += redQ[i][lane]; }
    float* sl = stats + (size_t)(blockIdx.x & (NSLICE - 1)) * 128;
    atomicAdd(&sl[lane], s);
    atomicAdd(&sl[64 + lane], qq);
  }
  // ---- fused BN-fold: last block to finish does prep ----
  __shared__ int lastFlag;
  if (t == 0) {
    __threadfence();
    int done = atomicAdd(layerDone, 1);
    lastFlag = (done == (int)gridDim.x - 1);
  }
  __syncthreads();
  if (!lastFlag) return;
  __threadfence();
  __shared__ float tmp[128];
  __shared__ float alpha[64];
  __shared__ float beta[64];
  if (t < 128) {
    float s = 0.f;
    for (int i = 0; i < NSLICE; ++i)
      s += __hip_atomic_load(&stats[(size_t)i * 128 + t], __ATOMIC_RELAXED,
                             __HIP_MEMORY_SCOPE_AGENT);
    tmp[t] = s;
  }
  __syncthreads();
  if (t < 64) {
    float m = tmp[t] / (float)N_NODES;
    float var = tmp[64 + t] / (float)N_NODES - m * m;
    float a = g[t] * rsqrtf(var + BN_EPS);
    alpha[t] = a;
    float bt = be[t] - m * a;
    beta[t] = bt;
    ab[t] = a;
    ab[64 + t] = bt;
  }
  __syncthreads();
  if (hasNext) {
    for (int idx = t; idx < HID * HID; idx += 256) {
      int j = idx & 7, lane2 = (idx >> 3) & 63, rest = idx >> 9;
      int kc = rest & 1, nt = rest >> 1;
      int k = kc * 32 + ((lane2 >> 4) & 3) * 8 + j;
      int nn = nt * 16 + (lane2 & 15);
      Wsw[idx] = bf1_pack(alpha[k] * Wnext[k * HID + nn]);
    }
    if (t < 64) {
      float c = 0.f;
      for (int k = 0; k < HID; ++k) c += beta[k] * Wnext[k * HID + t];
      cvecOut[t] = c;
    }
  }
}

// ---------------- pool (bf16 Z) ----------------

#define POOL_CH 64

__global__ __launch_bounds__(256) void pool_kernel(
    const unsigned short* __restrict__ Z, const int* __restrict__ batch,
    const float* __restrict__ ab, float* __restrict__ out) {
  int tid = blockIdx.x * blockDim.x + threadIdx.x;
  int w = tid >> 6, lane = tid & 63;
  int v0 = w * POOL_CH;
  if (v0 >= N_NODES) return;
  int v1 = min(N_NODES, v0 + POOL_CH);
  float a = ab[lane], b = ab[64 + lane];
  float acc = 0.f;
  int cur = batch[v0];
  for (int v = v0; v < v1; ++v) {
    int bg = batch[v];
    if (bg != cur) {
      atomicAdd(&out[(size_t)cur * HID + lane], acc);
      acc = 0.f;
      cur = bg;
    }
    acc = fmaf(bf1_unpack(Z[(size_t)v * HID + lane]), a, acc + b);
  }
  atomicAdd(&out[(size_t)cur * HID + lane], acc);
}

// ---------------- launch ----------------

extern "C" void kernel_launch(void* const* d_in, const int* in_sizes, int n_in,
                              void* d_out, int out_size, void* d_ws, size_t ws_size,
                              hipStream_t stream) {
  const float* x    = (const float*)d_in[0];
  const int* src    = (const int*)d_in[1];
  const int* dst    = (const int*)d_in[2];
  const int* batch  = (const int*)d_in[3];
  const float* W[4]  = {(const float*)d_in[4], (const float*)d_in[8],
                        (const float*)d_in[12], (const float*)d_in[16]};
  const float* b[4]  = {(const float*)d_in[5], (const float*)d_in[9],
                        (const float*)d_in[13], (const float*)d_in[17]};
  const float* g[4]  = {(const float*)d_in[6], (const float*)d_in[10],
                        (const float*)d_in[14], (const float*)d_in[18]};
  const float* be[4] = {(const float*)d_in[7], (const float*)d_in[11],
                        (const float*)d_in[15], (const float*)d_in[19]};

  char* wsb = (char*)d_ws;
  size_t off = 0;
  auto alloc = [&](size_t bytes) -> void* {
    void* p = wsb + off;
    off += (bytes + 255) & ~(size_t)255;
    return p;
  };
  // zeroed region (one memset)
  int*   binCur = (int*)  alloc((size_t)NBIN * 4);
  int*   layerDone = (int*)alloc(4 * 4);
  float* c0     = (float*)alloc(64 * 4);
  float* stats  = (float*)alloc((size_t)4 * NSLICE * 128 * 4);
  size_t zero_bytes = off;
  // non-zeroed
  int*   binBase= (int*)  alloc((size_t)(NBIN + 1) * 4);
  float* Ssum   = (float*)alloc((size_t)N_NODES * 4);
  int*   rowptr = (int*)  alloc((size_t)(N_NODES + 1) * 4);
  float* dinv   = (float*)alloc((size_t)N_NODES * 4);
  unsigned* staging = (unsigned*)alloc((size_t)NBIN * BCAP * 4);
  int*   csr    = (int*)  alloc((size_t)N_EDGES * 4);
  unsigned short* Hb  = (unsigned short*)alloc((size_t)N_NODES * HID * 2);
  unsigned short* Zb  = (unsigned short*)alloc((size_t)N_NODES * HID * 2);
  unsigned short* Wsw = (unsigned short*)alloc((size_t)HID * HID * 2);
  float* cv     = (float*)alloc(64 * 4);
  float* ab     = (float*)alloc(128 * 4);

  hipMemsetAsync(d_ws, 0, zero_bytes, stream);
  hipMemsetAsync(d_out, 0, (size_t)out_size * 4, stream);

  bin_kernel<<<BIN_BLOCKS, 256, 0, stream>>>(src, dst, binCur, staging);
  binscan_kernel<<<1, 256, 0, stream>>>(binCur, binBase, rowptr);
  sort_kernel<<<NBIN, 256, 0, stream>>>(staging, binCur, binBase, dinv, rowptr, csr);
  ssum_kernel<<<(N_NODES + 255) / 256, 256, 0, stream>>>(csr, rowptr, dinv, Ssum);

  int gemmBlocks = (N_NODES + 63) / 64;
  int aggBlocks = (N_NODES + AGG_WAVES * 8 - 1) / (AGG_WAVES * 8);

  // layer 1 (K=75, c=0); agg epilogue folds BN and builds Wsw for layer 2
  gemm1_kernel<<<gemmBlocks, 256, 0, stream>>>(x, W[0], dinv, Hb);
  agg_kernel<<<aggBlocks, 256, 0, stream>>>(Hb, csr, rowptr, Ssum, dinv, c0, b[0], Zb,
                                            stats, layerDone, g[0], be[0], W[1], Wsw,
                                            cv, ab, 1);

  // layers 2..4
  for (int l = 1; l < 4; ++l) {
    gemmB_kernel<<<gemmBlocks, 256, 0, stream>>>(Zb, Wsw, dinv, Hb);
    agg_kernel<<<aggBlocks, 256, 0, stream>>>(Hb, csr, rowptr, Ssum, dinv, cv, b[l], Zb,
                                              stats + (size_t)l * NSLICE * 128,
                                              layerDone + l, g[l], be[l],
                                              (l < 3) ? W[l + 1] : nullptr, Wsw,
                                              cv, ab, (l < 3) ? 1 : 0);
  }

  int poolBlocks = (N_NODES + 4 * POOL_CH - 1) / (4 * POOL_CH);
  pool_kernel<<<poolBlocks, 256, 0, stream>>>(Zb, batch, ab, (float*)d_out);
}

// Round 13
// 404.899 us; speedup vs baseline: 1.9729x; 1.9729x over previous
//
#include <hip/hip_runtime.h>
#include <hip/hip_bf16.h>
#include <math.h>

#define N_NODES 100000
#define N_EDGES 1600000
#define N_FEAT 75
#define HID 64
#define NUM_GRAPHS 4096
#define BN_EPS 1e-5f
#define NSLICE 64

#define NBIN 400          // bins of 250 nodes
#define NPB 250
#define BCAP 4800         // staging capacity per bin
#define CSRCAP 6552       // padded csr capacity per bin (multiple of 8; mean 4875, +25 sigma)
#define BIN_BLOCKS 256
#define BIN_CHUNK ((N_EDGES + BIN_BLOCKS - 1) / BIN_BLOCKS)   // 6250

#define XPAD 68           // LDS row stride (words): 16B-aligned, bank-shift 4

typedef short bf16x8 __attribute__((ext_vector_type(8)));
typedef float f32x4 __attribute__((ext_vector_type(4)));

// ---------------- bf16 helpers ----------------

__device__ __forceinline__ unsigned bf2_pack(float a, float b) {
  unsigned ua = __float_as_uint(a); ua += 0x7FFF + ((ua >> 16) & 1);
  unsigned ub = __float_as_uint(b); ub += 0x7FFF + ((ub >> 16) & 1);
  return (ua >> 16) | (ub & 0xFFFF0000u);
}
__device__ __forceinline__ unsigned short bf1_pack(float a) {
  unsigned ua = __float_as_uint(a); ua += 0x7FFF + ((ua >> 16) & 1);
  return (unsigned short)(ua >> 16);
}
__device__ __forceinline__ float4 bf4_unpack(uint2 u) {
  return make_float4(__uint_as_float(u.x << 16), __uint_as_float(u.x & 0xFFFF0000u),
                     __uint_as_float(u.y << 16), __uint_as_float(u.y & 0xFFFF0000u));
}
__device__ __forceinline__ float bf1_unpack(unsigned short u) {
  return __uint_as_float((unsigned)u << 16);
}

// ---------------- setup: LDS-binned counting sort into PADDED per-bin csr --------------
// Each node's edge list is padded to a multiple of 8 with sentinel N_NODES (a zero row
// in Hs / dinv) -> agg loop is tail-free, mask-free, and csr chunks are 16B-aligned.

__global__ __launch_bounds__(256) void bin_kernel(const int* __restrict__ src,
                                                  const int* __restrict__ dst,
                                                  int* __restrict__ binCur,
                                                  unsigned* __restrict__ staging) {
  __shared__ unsigned ent[BIN_CHUNK];
  __shared__ short binv[BIN_CHUNK];
  __shared__ int lcnt[NBIN];
  __shared__ int lbase[NBIN];
  int t = threadIdx.x;
  int c0 = blockIdx.x * BIN_CHUNK;
  int c1 = min(c0 + BIN_CHUNK, N_EDGES);
  int n = c1 - c0;
  for (int i = t; i < NBIN; i += 256) lcnt[i] = 0;
  __syncthreads();
  for (int i = t; i < n; i += 256) {
    int d = dst[c0 + i];
    int s = src[c0 + i];
    int b = d / NPB;
    int ld = d - b * NPB;
    ent[i] = ((unsigned)ld << 17) | (unsigned)s;
    binv[i] = (short)b;
    atomicAdd(&lcnt[b], 1);
  }
  __syncthreads();
  for (int i = t; i < NBIN; i += 256)
    lbase[i] = atomicAdd(&binCur[i], lcnt[i]);
  __syncthreads();
  for (int i = t; i < n; i += 256) {
    int b = binv[i];
    int slot = atomicAdd(&lbase[b], 1);
    if (slot < BCAP) staging[(size_t)b * BCAP + slot] = ent[i];
  }
}

__global__ __launch_bounds__(256) void sort_kernel(const unsigned* __restrict__ staging,
                                                   const int* __restrict__ binCur,
                                                   float* __restrict__ dinv,
                                                   int* __restrict__ rowS,
                                                   int* __restrict__ rowE,
                                                   int* __restrict__ csr) {
  __shared__ unsigned in[BCAP];
  __shared__ int outw[CSRCAP];
  __shared__ int cnt[NPB];
  __shared__ int pexcl[256];
  __shared__ int ptot;
  int b = blockIdx.x, t = threadIdx.x;
  int n = min(binCur[b], BCAP);
  const unsigned* st = staging + (size_t)b * BCAP;
  for (int i = t; i < NPB; i += 256) cnt[i] = 0;
  __syncthreads();
  for (int i = t; i < n; i += 256) {
    unsigned e = st[i];
    in[i] = e;
    atomicAdd(&cnt[e >> 17], 1);
  }
  __syncthreads();
  int deg = (t < NPB) ? cnt[t] : 0;
  int pdeg = (deg + 7) & ~7;            // pad to multiple of 8
  pexcl[t] = pdeg;
  __syncthreads();
  for (int off = 1; off < 256; off <<= 1) {
    int a = (t >= off) ? pexcl[t - off] : 0;
    __syncthreads();
    pexcl[t] += a;
    __syncthreads();
  }
  int excl = pexcl[t] - pdeg;
  if (t == 255) ptot = pexcl[255];
  int base = b * CSRCAP;
  if (t < NPB) {
    int v = b * NPB + t;
    dinv[v] = rsqrtf((float)deg + 1.0f);
    rowS[v] = base + excl;
    rowE[v] = base + excl + pdeg;
    cnt[t] = excl;                      // local cursor
  }
  if (b == 0 && t == 0) dinv[N_NODES] = 0.f;   // sentinel
  __syncthreads();
  int ptotal = min(ptot, CSRCAP);
  for (int i = t; i < ptotal; i += 256) outw[i] = N_NODES;   // sentinel fill
  __syncthreads();
  for (int i = t; i < n; i += 256) {
    unsigned e = in[i];
    int p = atomicAdd(&cnt[e >> 17], 1);
    if (p < CSRCAP) outw[p] = (int)(e & 0x1FFFFu);
  }
  __syncthreads();
  for (int i = t; i < ptotal; i += 256) csr[base + i] = outw[i];
}

// S[v] = dv*(dv + sum of dinv[src]); sentinel dinv = 0 -> no masking
__global__ void ssum_kernel(const int* __restrict__ csr, const int* __restrict__ rowS,
                            const int* __restrict__ rowE, const float* __restrict__ dinv,
                            float* __restrict__ Ssum) {
  int v = blockIdx.x * blockDim.x + threadIdx.x;
  if (v >= N_NODES) return;
  float dv = dinv[v];
  float s = dv;
  int e1 = rowE[v];
  for (int e = rowS[v]; e < e1; e += 8) {
    int4 a = *(const int4*)&csr[e];
    int4 b2 = *(const int4*)&csr[e + 4];
    s += ((dinv[a.x] + dinv[a.y]) + (dinv[a.z] + dinv[a.w])) +
         ((dinv[b2.x] + dinv[b2.y]) + (dinv[b2.z] + dinv[b2.w]));
  }
  Ssum[v] = dv * s;
}

// ---------------- GEMM layer 1: fp32 X [N,75] @ W -> bf16 Hs (VALU) ----------------
// Also writes the zero sentinel row Hs[N_NODES].

__global__ __launch_bounds__(256) void gemm1_kernel(
    const float* __restrict__ X, const float* __restrict__ W,
    const float* __restrict__ dinv, unsigned short* __restrict__ Hout) {
  __shared__ float xs[N_FEAT][XPAD];   // [k][row]
  __shared__ float ws[N_FEAT][64];     // [k][col]
  int t = threadIdx.x;
  int rowBase = blockIdx.x * 64;
  for (int i = t; i < N_FEAT * 64; i += 256) ws[i >> 6][i & 63] = W[i];
  if (rowBase + 64 <= N_NODES) {
    const float* Xb = X + (size_t)rowBase * N_FEAT;
    for (int i = t; i < 64 * N_FEAT; i += 256) {
      int r = i / N_FEAT, k = i - r * N_FEAT;
      xs[k][r] = Xb[i];
    }
  } else {
    for (int i = t; i < 64 * N_FEAT; i += 256) {
      int r = i / N_FEAT, k = i - r * N_FEAT;
      int row = rowBase + r;
      xs[k][r] = (row < N_NODES) ? X[(size_t)row * N_FEAT + k] : 0.f;
    }
  }
  __syncthreads();
  int ty = t >> 4, tx = t & 15;
  int r0 = ty * 4, c0 = tx * 4;
  float acc[4][4] = {};
  for (int k = 0; k < N_FEAT; ++k) {
    float4 a = *(const float4*)&xs[k][r0];
    float4 bq = *(const float4*)&ws[k][c0];
    float av[4] = {a.x, a.y, a.z, a.w};
    float bv[4] = {bq.x, bq.y, bq.z, bq.w};
    #pragma unroll
    for (int i = 0; i < 4; ++i)
      #pragma unroll
      for (int j = 0; j < 4; ++j)
        acc[i][j] = fmaf(av[i], bv[j], acc[i][j]);
  }
  #pragma unroll
  for (int i = 0; i < 4; ++i) {
    int row = rowBase + r0 + i;
    if (row < N_NODES) {
      float dv = dinv[row];
      uint2 packed = make_uint2(bf2_pack(acc[i][0] * dv, acc[i][1] * dv),
                                bf2_pack(acc[i][2] * dv, acc[i][3] * dv));
      *(uint2*)&Hout[(size_t)row * HID + c0] = packed;
    } else if (row == N_NODES) {
      *(uint2*)&Hout[(size_t)row * HID + c0] = make_uint2(0u, 0u);
    }
  }
}

// ---------------- GEMM layers 2-4 (MFMA): bf16 Z [N,64] @ bf16 Wsw -> bf16 Hs ---------

__global__ __launch_bounds__(256) void gemmB_kernel(
    const unsigned short* __restrict__ Zin, const unsigned short* __restrict__ Wsw,
    const float* __restrict__ dinv, unsigned short* __restrict__ Hout) {
  __shared__ float ldsC[64][XPAD];
  int t = threadIdx.x;
  int w = t >> 6, lane = t & 63;
  int quad = lane >> 4, li = lane & 15;
  int row0 = blockIdx.x * 64;
  int rowA = row0 + w * 16 + li;
  if (rowA >= N_NODES) rowA = N_NODES - 1;
  const bf16x8* Zr = (const bf16x8*)(Zin + (size_t)rowA * HID + quad * 8);
  bf16x8 a0 = Zr[0];               // kc=0: k = quad*8 + j
  bf16x8 a1 = Zr[4];               // kc=1: +32 shorts
  const bf16x8* Wr = (const bf16x8*)Wsw;
  f32x4 accs[4];
  #pragma unroll
  for (int nt = 0; nt < 4; ++nt) {
    bf16x8 b0 = Wr[(nt * 2 + 0) * 64 + lane];
    bf16x8 b1 = Wr[(nt * 2 + 1) * 64 + lane];
    f32x4 acc = {0.f, 0.f, 0.f, 0.f};
    acc = __builtin_amdgcn_mfma_f32_16x16x32_bf16(a0, b0, acc, 0, 0, 0);
    acc = __builtin_amdgcn_mfma_f32_16x16x32_bf16(a1, b1, acc, 0, 0, 0);
    accs[nt] = acc;
  }
  float dv[4];
  #pragma unroll
  for (int r = 0; r < 4; ++r) {
    int rr = row0 + w * 16 + quad * 4 + r;
    dv[r] = dinv[min(rr, N_NODES - 1)];
  }
  #pragma unroll
  for (int nt = 0; nt < 4; ++nt)
    #pragma unroll
    for (int r = 0; r < 4; ++r)
      ldsC[w * 16 + quad * 4 + r][nt * 16 + li] = accs[nt][r] * dv[r];
  __syncthreads();
  int rl = t >> 2, c0 = (t & 3) * 16;
  int row = row0 + rl;
  if (row < N_NODES) {
    unsigned p[8];
    #pragma unroll
    for (int j = 0; j < 8; ++j)
      p[j] = bf2_pack(ldsC[rl][c0 + 2 * j], ldsC[rl][c0 + 2 * j + 1]);
    uint4* dst0 = (uint4*)(Hout + (size_t)row * HID + c0);
    dst0[0] = make_uint4(p[0], p[1], p[2], p[3]);
    dst0[1] = make_uint4(p[4], p[5], p[6], p[7]);
  } else if (row == N_NODES) {
    uint4* dst0 = (uint4*)(Hout + (size_t)row * HID + c0);
    dst0[0] = make_uint4(0u, 0u, 0u, 0u);
    dst0[1] = make_uint4(0u, 0u, 0u, 0u);
  }
}

// ---------------- aggregation + relu + BN-stats (padded csr: no tails, no masks) -------

#define AGG_WAVES 4
#define AGG_NPN 2   // 32 nodes/block

__global__ __launch_bounds__(256) void agg_kernel(
    const unsigned short* __restrict__ Hs, const int* __restrict__ csr,
    const int* __restrict__ rowS, const int* __restrict__ rowE,
    const float* __restrict__ S, const float* __restrict__ dinv,
    const float* __restrict__ cvec, const float* __restrict__ bias,
    unsigned short* __restrict__ Z, float* __restrict__ stats) {
  int t = threadIdx.x;
  int wave = t >> 6, lane = t & 63;
  int q = lane >> 4, li = lane & 15;
  int f = li * 4;
  int nodeBase = blockIdx.x * (AGG_WAVES * 4 * AGG_NPN) + wave * (4 * AGG_NPN) + q;
  float4 cl = *(const float4*)&cvec[f];
  float4 bl = *(const float4*)&bias[f];
  float4 ssum = make_float4(0.f, 0.f, 0.f, 0.f);
  float4 ssq  = make_float4(0.f, 0.f, 0.f, 0.f);
  #pragma unroll
  for (int it = 0; it < AGG_NPN; ++it) {
    int v = nodeBase + 4 * it;
    if (v < N_NODES) {
      float4 acc = bf4_unpack(*(const uint2*)&Hs[(size_t)v * HID + f]);
      int e1 = rowE[v];
      for (int e = rowS[v]; e < e1; e += 8) {
        int4 cA = *(const int4*)&csr[e];
        int4 cB = *(const int4*)&csr[e + 4];
        uint2 u0 = *(const uint2*)&Hs[(size_t)cA.x * HID + f];
        uint2 u1 = *(const uint2*)&Hs[(size_t)cA.y * HID + f];
        uint2 u2 = *(const uint2*)&Hs[(size_t)cA.z * HID + f];
        uint2 u3 = *(const uint2*)&Hs[(size_t)cA.w * HID + f];
        uint2 u4 = *(const uint2*)&Hs[(size_t)cB.x * HID + f];
        uint2 u5 = *(const uint2*)&Hs[(size_t)cB.y * HID + f];
        uint2 u6 = *(const uint2*)&Hs[(size_t)cB.z * HID + f];
        uint2 u7 = *(const uint2*)&Hs[(size_t)cB.w * HID + f];
        float4 h0 = bf4_unpack(u0), h1 = bf4_unpack(u1);
        float4 h2 = bf4_unpack(u2), h3 = bf4_unpack(u3);
        float4 h4 = bf4_unpack(u4), h5 = bf4_unpack(u5);
        float4 h6 = bf4_unpack(u6), h7 = bf4_unpack(u7);
        acc.x += ((h0.x + h1.x) + (h2.x + h3.x)) + ((h4.x + h5.x) + (h6.x + h7.x));
        acc.y += ((h0.y + h1.y) + (h2.y + h3.y)) + ((h4.y + h5.y) + (h6.y + h7.y));
        acc.z += ((h0.z + h1.z) + (h2.z + h3.z)) + ((h4.z + h5.z) + (h6.z + h7.z));
        acc.w += ((h0.w + h1.w) + (h2.w + h3.w)) + ((h4.w + h5.w) + (h6.w + h7.w));
      }
      float dv = dinv[v], sv = S[v];
      float4 z;
      z.x = fmaxf(fmaf(dv, acc.x, fmaf(sv, cl.x, bl.x)), 0.f);
      z.y = fmaxf(fmaf(dv, acc.y, fmaf(sv, cl.y, bl.y)), 0.f);
      z.z = fmaxf(fmaf(dv, acc.z, fmaf(sv, cl.z, bl.z)), 0.f);
      z.w = fmaxf(fmaf(dv, acc.w, fmaf(sv, cl.w, bl.w)), 0.f);
      *(uint2*)&Z[(size_t)v * HID + f] = make_uint2(bf2_pack(z.x, z.y), bf2_pack(z.z, z.w));
      ssum.x += z.x; ssum.y += z.y; ssum.z += z.z; ssum.w += z.w;
      ssq.x += z.x * z.x; ssq.y += z.y * z.y; ssq.z += z.z * z.z; ssq.w += z.w * z.w;
    }
  }
  #pragma unroll
  for (int m = 16; m <= 32; m <<= 1) {
    ssum.x += __shfl_xor(ssum.x, m); ssum.y += __shfl_xor(ssum.y, m);
    ssum.z += __shfl_xor(ssum.z, m); ssum.w += __shfl_xor(ssum.w, m);
    ssq.x  += __shfl_xor(ssq.x,  m); ssq.y  += __shfl_xor(ssq.y,  m);
    ssq.z  += __shfl_xor(ssq.z,  m); ssq.w  += __shfl_xor(ssq.w,  m);
  }
  __shared__ float redS[AGG_WAVES][64];
  __shared__ float redQ[AGG_WAVES][64];
  if (q == 0) {
    *(float4*)&redS[wave][f] = ssum;
    *(float4*)&redQ[wave][f] = ssq;
  }
  __syncthreads();
  if (wave == 0) {
    float s = 0.f, qq = 0.f;
    #pragma unroll
    for (int i = 0; i < AGG_WAVES; ++i) { s += redS[i][lane]; qq += redQ[i][lane]; }
    float* sl = stats + (size_t)(blockIdx.x & (NSLICE - 1)) * 128;
    atomicAdd(&sl[lane], s);
    atomicAdd(&sl[64 + lane], qq);
  }
}

// ---------------- BN fold: alpha/beta, Wsw = swizzled bf16(alpha⊙W), c = beta@W -------

__global__ __launch_bounds__(256) void prep_kernel(
    const float* __restrict__ stats, const float* __restrict__ g,
    const float* __restrict__ be, const float* __restrict__ Wnext,
    unsigned short* __restrict__ Wsw, float* __restrict__ cvec,
    float* __restrict__ ab, int hasNext) {
  __shared__ float tmp[128];
  __shared__ float alpha[64];
  __shared__ float beta[64];
  int t = threadIdx.x;
  if (t < 128) {
    float s = 0.f;
    for (int i = 0; i < NSLICE; ++i) s += stats[(size_t)i * 128 + t];
    tmp[t] = s;
  }
  __syncthreads();
  if (t < 64) {
    float m = tmp[t] / (float)N_NODES;
    float var = tmp[64 + t] / (float)N_NODES - m * m;
    float a = g[t] * rsqrtf(var + BN_EPS);
    alpha[t] = a;
    float bt = be[t] - m * a;
    beta[t] = bt;
    ab[t] = a;
    ab[64 + t] = bt;
  }
  __syncthreads();
  if (hasNext) {
    // B-fragment swizzle for mfma_f32_16x16x32_bf16
    for (int idx = t; idx < HID * HID; idx += 256) {
      int j = idx & 7, lane2 = (idx >> 3) & 63, rest = idx >> 9;
      int kc = rest & 1, nt = rest >> 1;
      int k = kc * 32 + ((lane2 >> 4) & 3) * 8 + j;
      int nn = nt * 16 + (lane2 & 15);
      Wsw[idx] = bf1_pack(alpha[k] * Wnext[k * HID + nn]);
    }
    if (t < 64) {
      float c = 0.f;
      for (int k = 0; k < HID; ++k) c += beta[k] * Wnext[k * HID + t];
      cvec[t] = c;
    }
  }
}

// ---------------- pool (bf16 Z) ----------------

#define POOL_CH 64

__global__ __launch_bounds__(256) void pool_kernel(
    const unsigned short* __restrict__ Z, const int* __restrict__ batch,
    const float* __restrict__ ab, float* __restrict__ out) {
  int tid = blockIdx.x * blockDim.x + threadIdx.x;
  int w = tid >> 6, lane = tid & 63;
  int v0 = w * POOL_CH;
  if (v0 >= N_NODES) return;
  int v1 = min(N_NODES, v0 + POOL_CH);
  float a = ab[lane], b = ab[64 + lane];
  float acc = 0.f;
  int cur = batch[v0];
  for (int v = v0; v < v1; ++v) {
    int bg = batch[v];
    if (bg != cur) {
      atomicAdd(&out[(size_t)cur * HID + lane], acc);
      acc = 0.f;
      cur = bg;
    }
    acc = fmaf(bf1_unpack(Z[(size_t)v * HID + lane]), a, acc + b);
  }
  atomicAdd(&out[(size_t)cur * HID + lane], acc);
}

// ---------------- launch ----------------

extern "C" void kernel_launch(void* const* d_in, const int* in_sizes, int n_in,
                              void* d_out, int out_size, void* d_ws, size_t ws_size,
                              hipStream_t stream) {
  const float* x    = (const float*)d_in[0];
  const int* src    = (const int*)d_in[1];
  const int* dst    = (const int*)d_in[2];
  const int* batch  = (const int*)d_in[3];
  const float* W[4]  = {(const float*)d_in[4], (const float*)d_in[8],
                        (const float*)d_in[12], (const float*)d_in[16]};
  const float* b[4]  = {(const float*)d_in[5], (const float*)d_in[9],
                        (const float*)d_in[13], (const float*)d_in[17]};
  const float* g[4]  = {(const float*)d_in[6], (const float*)d_in[10],
                        (const float*)d_in[14], (const float*)d_in[18]};
  const float* be[4] = {(const float*)d_in[7], (const float*)d_in[11],
                        (const float*)d_in[15], (const float*)d_in[19]};

  char* wsb = (char*)d_ws;
  size_t off = 0;
  auto alloc = [&](size_t bytes) -> void* {
    void* p = wsb + off;
    off += (bytes + 255) & ~(size_t)255;
    return p;
  };
  // zeroed region (one memset)
  int*   binCur = (int*)  alloc((size_t)NBIN * 4);
  float* c0     = (float*)alloc(64 * 4);
  float* stats  = (float*)alloc((size_t)4 * NSLICE * 128 * 4);
  size_t zero_bytes = off;
  // non-zeroed
  float* Ssum   = (float*)alloc((size_t)N_NODES * 4);
  int*   rowS   = (int*)  alloc((size_t)N_NODES * 4);
  int*   rowE   = (int*)  alloc((size_t)N_NODES * 4);
  float* dinv   = (float*)alloc((size_t)(N_NODES + 1) * 4);
  unsigned* staging = (unsigned*)alloc((size_t)NBIN * BCAP * 4);
  int*   csr    = (int*)  alloc((size_t)NBIN * CSRCAP * 4);
  unsigned short* Hb  = (unsigned short*)alloc((size_t)(N_NODES + 1) * HID * 2);
  unsigned short* Zb  = (unsigned short*)alloc((size_t)N_NODES * HID * 2);
  unsigned short* Wsw = (unsigned short*)alloc((size_t)HID * HID * 2);
  float* cv     = (float*)alloc(64 * 4);
  float* ab     = (float*)alloc(128 * 4);

  hipMemsetAsync(d_ws, 0, zero_bytes, stream);
  hipMemsetAsync(d_out, 0, (size_t)out_size * 4, stream);

  bin_kernel<<<BIN_BLOCKS, 256, 0, stream>>>(src, dst, binCur, staging);
  sort_kernel<<<NBIN, 256, 0, stream>>>(staging, binCur, dinv, rowS, rowE, csr);
  ssum_kernel<<<(N_NODES + 255) / 256, 256, 0, stream>>>(csr, rowS, rowE, dinv, Ssum);

  int gemmBlocks = (N_NODES + 64) / 64;   // covers sentinel row N_NODES
  int nodesPerAggBlock = AGG_WAVES * 4 * AGG_NPN;
  int aggBlocks = (N_NODES + nodesPerAggBlock - 1) / nodesPerAggBlock;

  // layer 1 (K=75, c=0)
  gemm1_kernel<<<gemmBlocks, 256, 0, stream>>>(x, W[0], dinv, Hb);
  agg_kernel<<<aggBlocks, 256, 0, stream>>>(Hb, csr, rowS, rowE, Ssum, dinv, c0, b[0],
                                            Zb, stats);
  prep_kernel<<<1, 256, 0, stream>>>(stats, g[0], be[0], W[1], Wsw, cv, ab, 1);

  // layers 2..4
  for (int l = 1; l < 4; ++l) {
    gemmB_kernel<<<gemmBlocks, 256, 0, stream>>>(Zb, Wsw, dinv, Hb);
    agg_kernel<<<aggBlocks, 256, 0, stream>>>(Hb, csr, rowS, rowE, Ssum, dinv, cv, b[l],
                                              Zb, stats + (size_t)l * NSLICE * 128);
    prep_kernel<<<1, 256, 0, stream>>>(stats + (size_t)l * NSLICE * 128, g[l], be[l],
                                       (l < 3) ? W[l + 1] : nullptr, Wsw, cv, ab,
                                       (l < 3) ? 1 : 0);
  }

  int poolBlocks = (N_NODES + 4 * POOL_CH - 1) / (4 * POOL_CH);
  pool_kernel<<<poolBlocks, 256, 0, stream>>>(Zb, batch, ab, (float*)d_out);
}

// Round 14
// 399.189 us; speedup vs baseline: 2.0011x; 1.0143x over previous
//
#include <hip/hip_runtime.h>
#include <hip/hip_bf16.h>
#include <math.h>

#define N_NODES 100000
#define N_EDGES 1600000
#define N_FEAT 75
#define HID 64
#define NUM_GRAPHS 4096
#define BN_EPS 1e-5f
#define NSLICE 64

#define NBIN 400          // bins of 250 nodes
#define NPB 250
#define BCAP 4800         // staging capacity per bin
#define CSRCAP 6552       // padded csr capacity per bin (multiple of 8)
#define BIN_BLOCKS 256
#define BIN_CHUNK ((N_EDGES + BIN_BLOCKS - 1) / BIN_BLOCKS)   // 6250

#define XPAD 68           // LDS row stride (words): 16B-aligned, bank-shift 4

typedef short bf16x8 __attribute__((ext_vector_type(8)));
typedef float f32x4 __attribute__((ext_vector_type(4)));

// ---------------- bf16 helpers ----------------

__device__ __forceinline__ unsigned bf2_pack(float a, float b) {
  unsigned ua = __float_as_uint(a); ua += 0x7FFF + ((ua >> 16) & 1);
  unsigned ub = __float_as_uint(b); ub += 0x7FFF + ((ub >> 16) & 1);
  return (ua >> 16) | (ub & 0xFFFF0000u);
}
__device__ __forceinline__ unsigned short bf1_pack(float a) {
  unsigned ua = __float_as_uint(a); ua += 0x7FFF + ((ua >> 16) & 1);
  return (unsigned short)(ua >> 16);
}
__device__ __forceinline__ float4 bf4_unpack(uint2 u) {
  return make_float4(__uint_as_float(u.x << 16), __uint_as_float(u.x & 0xFFFF0000u),
                     __uint_as_float(u.y << 16), __uint_as_float(u.y & 0xFFFF0000u));
}
__device__ __forceinline__ float bf1_unpack(unsigned short u) {
  return __uint_as_float((unsigned)u << 16);
}

// ---------------- setup: LDS-binned counting sort into PADDED, DEGREE-SORTED csr ------
// Nodes within each bin are ranked by degree; CSR segments laid out in rank order and
// perm[pos]=node. agg walks positions -> waves have near-uniform degree (no tail wait).

__global__ __launch_bounds__(256) void bin_kernel(const int* __restrict__ src,
                                                  const int* __restrict__ dst,
                                                  int* __restrict__ binCur,
                                                  unsigned* __restrict__ staging) {
  __shared__ unsigned ent[BIN_CHUNK];
  __shared__ short binv[BIN_CHUNK];
  __shared__ int lcnt[NBIN];
  __shared__ int lbase[NBIN];
  int t = threadIdx.x;
  int c0 = blockIdx.x * BIN_CHUNK;
  int c1 = min(c0 + BIN_CHUNK, N_EDGES);
  int n = c1 - c0;
  for (int i = t; i < NBIN; i += 256) lcnt[i] = 0;
  __syncthreads();
  for (int i = t; i < n; i += 256) {
    int d = dst[c0 + i];
    int s = src[c0 + i];
    int b = d / NPB;
    int ld = d - b * NPB;
    ent[i] = ((unsigned)ld << 17) | (unsigned)s;
    binv[i] = (short)b;
    atomicAdd(&lcnt[b], 1);
  }
  __syncthreads();
  for (int i = t; i < NBIN; i += 256)
    lbase[i] = atomicAdd(&binCur[i], lcnt[i]);
  __syncthreads();
  for (int i = t; i < n; i += 256) {
    int b = binv[i];
    int slot = atomicAdd(&lbase[b], 1);
    if (slot < BCAP) staging[(size_t)b * BCAP + slot] = ent[i];
  }
}

__global__ __launch_bounds__(256) void sort_kernel(const unsigned* __restrict__ staging,
                                                   const int* __restrict__ binCur,
                                                   float* __restrict__ dinv,
                                                   int2* __restrict__ rowSE,
                                                   int* __restrict__ perm,
                                                   int* __restrict__ csr) {
  __shared__ unsigned in[BCAP];
  __shared__ int outw[CSRCAP];
  __shared__ int cnt[NPB];
  __shared__ int hist[64];
  __shared__ int histCur[64];
  __shared__ int rnk[NPB];
  __shared__ int pd[256];
  __shared__ int ptot;
  int b = blockIdx.x, t = threadIdx.x;
  int n = min(binCur[b], BCAP);
  const unsigned* st = staging + (size_t)b * BCAP;
  for (int i = t; i < NPB; i += 256) cnt[i] = 0;
  if (t < 64) hist[t] = 0;
  __syncthreads();
  for (int i = t; i < n; i += 256) {
    unsigned e = st[i];
    in[i] = e;
    atomicAdd(&cnt[e >> 17], 1);
  }
  __syncthreads();
  int deg = (t < NPB) ? cnt[t] : 0;
  int db = min(deg, 63);
  if (t < NPB) atomicAdd(&hist[db], 1);
  __syncthreads();
  if (t < 64) {                       // exclusive scan of 64-bucket degree histogram
    int h = hist[t];
    int x = h;
    #pragma unroll
    for (int off = 1; off < 64; off <<= 1) {
      int y = __shfl_up(x, off);
      if (t >= off) x += y;
    }
    histCur[t] = x - h;
  }
  __syncthreads();
  int rank = 0;
  if (t < NPB) {
    rank = atomicAdd(&histCur[db], 1);  // unique rank, degree-ascending
    rnk[t] = rank;
  }
  pd[t] = 0;
  __syncthreads();
  int pdeg = (deg + 7) & ~7;
  if (t < NPB) pd[rank] = pdeg;
  __syncthreads();
  for (int off = 1; off < 256; off <<= 1) {   // inclusive scan of padded degrees (rank order)
    int a = (t >= off) ? pd[t - off] : 0;
    __syncthreads();
    pd[t] += a;
    __syncthreads();
  }
  if (t == 255) ptot = pd[255];
  __syncthreads();
  int base = b * CSRCAP;
  if (t < NPB) {
    int r = rnk[t];
    int excl = pd[r] - pdeg;
    int v = b * NPB + t;
    int pos = b * NPB + r;
    dinv[v] = rsqrtf((float)deg + 1.0f);
    rowSE[pos] = make_int2(base + excl, base + excl + pdeg);
    perm[pos] = v;
    cnt[t] = excl;                    // scatter cursor (node-local id)
  }
  if (b == 0 && t == 0) dinv[N_NODES] = 0.f;   // sentinel
  __syncthreads();
  int ptotal = min(ptot, CSRCAP);
  for (int i = t; i < ptotal; i += 256) outw[i] = N_NODES;   // sentinel fill
  __syncthreads();
  for (int i = t; i < n; i += 256) {
    unsigned e = in[i];
    int p = atomicAdd(&cnt[e >> 17], 1);
    if (p < CSRCAP) outw[p] = (int)(e & 0x1FFFFu);
  }
  __syncthreads();
  for (int i = t; i < ptotal; i += 256) csr[base + i] = outw[i];
}

// S[v] = dv*(dv + sum of dinv[src]); walks positions (wave-uniform degrees)
__global__ void ssum_kernel(const int* __restrict__ csr, const int2* __restrict__ rowSE,
                            const int* __restrict__ perm, const float* __restrict__ dinv,
                            float* __restrict__ Ssum) {
  int i = blockIdx.x * blockDim.x + threadIdx.x;
  if (i >= N_NODES) return;
  int v = perm[i];
  int2 se = rowSE[i];
  float dv = dinv[v];
  float s = dv;
  for (int e = se.x; e < se.y; e += 8) {
    int4 a = *(const int4*)&csr[e];
    int4 b2 = *(const int4*)&csr[e + 4];
    s += ((dinv[a.x] + dinv[a.y]) + (dinv[a.z] + dinv[a.w])) +
         ((dinv[b2.x] + dinv[b2.y]) + (dinv[b2.z] + dinv[b2.w]));
  }
  Ssum[v] = dv * s;
}

// ---------------- GEMM layer 1: fp32 X [N,75] @ W -> bf16 Hs (VALU) ----------------

__global__ __launch_bounds__(256) void gemm1_kernel(
    const float* __restrict__ X, const float* __restrict__ W,
    const float* __restrict__ dinv, unsigned short* __restrict__ Hout) {
  __shared__ float xs[N_FEAT][XPAD];   // [k][row]
  __shared__ float ws[N_FEAT][64];     // [k][col]
  int t = threadIdx.x;
  int rowBase = blockIdx.x * 64;
  for (int i = t; i < N_FEAT * 64; i += 256) ws[i >> 6][i & 63] = W[i];
  if (rowBase + 64 <= N_NODES) {
    const float* Xb = X + (size_t)rowBase * N_FEAT;
    for (int i = t; i < 64 * N_FEAT; i += 256) {
      int r = i / N_FEAT, k = i - r * N_FEAT;
      xs[k][r] = Xb[i];
    }
  } else {
    for (int i = t; i < 64 * N_FEAT; i += 256) {
      int r = i / N_FEAT, k = i - r * N_FEAT;
      int row = rowBase + r;
      xs[k][r] = (row < N_NODES) ? X[(size_t)row * N_FEAT + k] : 0.f;
    }
  }
  __syncthreads();
  int ty = t >> 4, tx = t & 15;
  int r0 = ty * 4, c0 = tx * 4;
  float acc[4][4] = {};
  for (int k = 0; k < N_FEAT; ++k) {
    float4 a = *(const float4*)&xs[k][r0];
    float4 bq = *(const float4*)&ws[k][c0];
    float av[4] = {a.x, a.y, a.z, a.w};
    float bv[4] = {bq.x, bq.y, bq.z, bq.w};
    #pragma unroll
    for (int i = 0; i < 4; ++i)
      #pragma unroll
      for (int j = 0; j < 4; ++j)
        acc[i][j] = fmaf(av[i], bv[j], acc[i][j]);
  }
  #pragma unroll
  for (int i = 0; i < 4; ++i) {
    int row = rowBase + r0 + i;
    if (row < N_NODES) {
      float dv = dinv[row];
      uint2 packed = make_uint2(bf2_pack(acc[i][0] * dv, acc[i][1] * dv),
                                bf2_pack(acc[i][2] * dv, acc[i][3] * dv));
      *(uint2*)&Hout[(size_t)row * HID + c0] = packed;
    } else if (row == N_NODES) {
      *(uint2*)&Hout[(size_t)row * HID + c0] = make_uint2(0u, 0u);
    }
  }
}

// ---------------- GEMM layers 2-4 (MFMA): bf16 Z [N,64] @ bf16 Wsw -> bf16 Hs ---------

__global__ __launch_bounds__(256) void gemmB_kernel(
    const unsigned short* __restrict__ Zin, const unsigned short* __restrict__ Wsw,
    const float* __restrict__ dinv, unsigned short* __restrict__ Hout) {
  __shared__ float ldsC[64][XPAD];
  int t = threadIdx.x;
  int w = t >> 6, lane = t & 63;
  int quad = lane >> 4, li = lane & 15;
  int row0 = blockIdx.x * 64;
  int rowA = row0 + w * 16 + li;
  if (rowA >= N_NODES) rowA = N_NODES - 1;
  const bf16x8* Zr = (const bf16x8*)(Zin + (size_t)rowA * HID + quad * 8);
  bf16x8 a0 = Zr[0];               // kc=0: k = quad*8 + j
  bf16x8 a1 = Zr[4];               // kc=1: +32 shorts
  const bf16x8* Wr = (const bf16x8*)Wsw;
  f32x4 accs[4];
  #pragma unroll
  for (int nt = 0; nt < 4; ++nt) {
    bf16x8 b0 = Wr[(nt * 2 + 0) * 64 + lane];
    bf16x8 b1 = Wr[(nt * 2 + 1) * 64 + lane];
    f32x4 acc = {0.f, 0.f, 0.f, 0.f};
    acc = __builtin_amdgcn_mfma_f32_16x16x32_bf16(a0, b0, acc, 0, 0, 0);
    acc = __builtin_amdgcn_mfma_f32_16x16x32_bf16(a1, b1, acc, 0, 0, 0);
    accs[nt] = acc;
  }
  float dv[4];
  #pragma unroll
  for (int r = 0; r < 4; ++r) {
    int rr = row0 + w * 16 + quad * 4 + r;
    dv[r] = dinv[min(rr, N_NODES - 1)];
  }
  #pragma unroll
  for (int nt = 0; nt < 4; ++nt)
    #pragma unroll
    for (int r = 0; r < 4; ++r)
      ldsC[w * 16 + quad * 4 + r][nt * 16 + li] = accs[nt][r] * dv[r];
  __syncthreads();
  int rl = t >> 2, c0 = (t & 3) * 16;
  int row = row0 + rl;
  if (row < N_NODES) {
    unsigned p[8];
    #pragma unroll
    for (int j = 0; j < 8; ++j)
      p[j] = bf2_pack(ldsC[rl][c0 + 2 * j], ldsC[rl][c0 + 2 * j + 1]);
    uint4* dst0 = (uint4*)(Hout + (size_t)row * HID + c0);
    dst0[0] = make_uint4(p[0], p[1], p[2], p[3]);
    dst0[1] = make_uint4(p[4], p[5], p[6], p[7]);
  } else if (row == N_NODES) {
    uint4* dst0 = (uint4*)(Hout + (size_t)row * HID + c0);
    dst0[0] = make_uint4(0u, 0u, 0u, 0u);
    dst0[1] = make_uint4(0u, 0u, 0u, 0u);
  }
}

// ---------------- aggregation + relu + BN-stats (degree-sorted positions) --------------

#define AGG_WAVES 4
#define AGG_NPN 2   // 32 positions/block

__global__ __launch_bounds__(256) void agg_kernel(
    const unsigned short* __restrict__ Hs, const int* __restrict__ csr,
    const int2* __restrict__ rowSE, const int* __restrict__ perm,
    const float* __restrict__ S, const float* __restrict__ dinv,
    const float* __restrict__ cvec, const float* __restrict__ bias,
    unsigned short* __restrict__ Z, float* __restrict__ stats) {
  int t = threadIdx.x;
  int wave = t >> 6, lane = t & 63;
  int q = lane >> 4, li = lane & 15;
  int f = li * 4;
  int posBase = blockIdx.x * (AGG_WAVES * 4 * AGG_NPN) + wave * (4 * AGG_NPN) + q;
  float4 cl = *(const float4*)&cvec[f];
  float4 bl = *(const float4*)&bias[f];
  float4 ssum = make_float4(0.f, 0.f, 0.f, 0.f);
  float4 ssq  = make_float4(0.f, 0.f, 0.f, 0.f);
  #pragma unroll
  for (int it = 0; it < AGG_NPN; ++it) {
    int i = posBase + 4 * it;
    if (i < N_NODES) {
      int v = perm[i];
      int2 se = rowSE[i];
      float4 acc = bf4_unpack(*(const uint2*)&Hs[(size_t)v * HID + f]);
      for (int e = se.x; e < se.y; e += 8) {
        int4 cA = *(const int4*)&csr[e];
        int4 cB = *(const int4*)&csr[e + 4];
        uint2 u0 = *(const uint2*)&Hs[(size_t)cA.x * HID + f];
        uint2 u1 = *(const uint2*)&Hs[(size_t)cA.y * HID + f];
        uint2 u2 = *(const uint2*)&Hs[(size_t)cA.z * HID + f];
        uint2 u3 = *(const uint2*)&Hs[(size_t)cA.w * HID + f];
        uint2 u4 = *(const uint2*)&Hs[(size_t)cB.x * HID + f];
        uint2 u5 = *(const uint2*)&Hs[(size_t)cB.y * HID + f];
        uint2 u6 = *(const uint2*)&Hs[(size_t)cB.z * HID + f];
        uint2 u7 = *(const uint2*)&Hs[(size_t)cB.w * HID + f];
        float4 h0 = bf4_unpack(u0), h1 = bf4_unpack(u1);
        float4 h2 = bf4_unpack(u2), h3 = bf4_unpack(u3);
        float4 h4 = bf4_unpack(u4), h5 = bf4_unpack(u5);
        float4 h6 = bf4_unpack(u6), h7 = bf4_unpack(u7);
        acc.x += ((h0.x + h1.x) + (h2.x + h3.x)) + ((h4.x + h5.x) + (h6.x + h7.x));
        acc.y += ((h0.y + h1.y) + (h2.y + h3.y)) + ((h4.y + h5.y) + (h6.y + h7.y));
        acc.z += ((h0.z + h1.z) + (h2.z + h3.z)) + ((h4.z + h5.z) + (h6.z + h7.z));
        acc.w += ((h0.w + h1.w) + (h2.w + h3.w)) + ((h4.w + h5.w) + (h6.w + h7.w));
      }
      float dv = dinv[v], sv = S[v];
      float4 z;
      z.x = fmaxf(fmaf(dv, acc.x, fmaf(sv, cl.x, bl.x)), 0.f);
      z.y = fmaxf(fmaf(dv, acc.y, fmaf(sv, cl.y, bl.y)), 0.f);
      z.z = fmaxf(fmaf(dv, acc.z, fmaf(sv, cl.z, bl.z)), 0.f);
      z.w = fmaxf(fmaf(dv, acc.w, fmaf(sv, cl.w, bl.w)), 0.f);
      *(uint2*)&Z[(size_t)v * HID + f] = make_uint2(bf2_pack(z.x, z.y), bf2_pack(z.z, z.w));
      ssum.x += z.x; ssum.y += z.y; ssum.z += z.z; ssum.w += z.w;
      ssq.x += z.x * z.x; ssq.y += z.y * z.y; ssq.z += z.z * z.z; ssq.w += z.w * z.w;
    }
  }
  #pragma unroll
  for (int m = 16; m <= 32; m <<= 1) {
    ssum.x += __shfl_xor(ssum.x, m); ssum.y += __shfl_xor(ssum.y, m);
    ssum.z += __shfl_xor(ssum.z, m); ssum.w += __shfl_xor(ssum.w, m);
    ssq.x  += __shfl_xor(ssq.x,  m); ssq.y  += __shfl_xor(ssq.y,  m);
    ssq.z  += __shfl_xor(ssq.z,  m); ssq.w  += __shfl_xor(ssq.w,  m);
  }
  __shared__ float redS[AGG_WAVES][64];
  __shared__ float redQ[AGG_WAVES][64];
  if (q == 0) {
    *(float4*)&redS[wave][f] = ssum;
    *(float4*)&redQ[wave][f] = ssq;
  }
  __syncthreads();
  if (wave == 0) {
    float s = 0.f, qq = 0.f;
    #pragma unroll
    for (int i = 0; i < AGG_WAVES; ++i) { s += redS[i][lane]; qq += redQ[i][lane]; }
    float* sl = stats + (size_t)(blockIdx.x & (NSLICE - 1)) * 128;
    atomicAdd(&sl[lane], s);
    atomicAdd(&sl[64 + lane], qq);
  }
}

// ---------------- BN fold: alpha/beta, Wsw = swizzled bf16(alpha⊙W), c = beta@W -------

__global__ __launch_bounds__(256) void prep_kernel(
    const float* __restrict__ stats, const float* __restrict__ g,
    const float* __restrict__ be, const float* __restrict__ Wnext,
    unsigned short* __restrict__ Wsw, float* __restrict__ cvec,
    float* __restrict__ ab, int hasNext) {
  __shared__ float tmp[128];
  __shared__ float alpha[64];
  __shared__ float beta[64];
  int t = threadIdx.x;
  if (t < 128) {
    float s = 0.f;
    for (int i = 0; i < NSLICE; ++i) s += stats[(size_t)i * 128 + t];
    tmp[t] = s;
  }
  __syncthreads();
  if (t < 64) {
    float m = tmp[t] / (float)N_NODES;
    float var = tmp[64 + t] / (float)N_NODES - m * m;
    float a = g[t] * rsqrtf(var + BN_EPS);
    alpha[t] = a;
    float bt = be[t] - m * a;
    beta[t] = bt;
    ab[t] = a;
    ab[64 + t] = bt;
  }
  __syncthreads();
  if (hasNext) {
    for (int idx = t; idx < HID * HID; idx += 256) {
      int j = idx & 7, lane2 = (idx >> 3) & 63, rest = idx >> 9;
      int kc = rest & 1, nt = rest >> 1;
      int k = kc * 32 + ((lane2 >> 4) & 3) * 8 + j;
      int nn = nt * 16 + (lane2 & 15);
      Wsw[idx] = bf1_pack(alpha[k] * Wnext[k * HID + nn]);
    }
    if (t < 64) {
      float c = 0.f;
      for (int k = 0; k < HID; ++k) c += beta[k] * Wnext[k * HID + t];
      cvec[t] = c;
    }
  }
}

// ---------------- pool (bf16 Z) ----------------

#define POOL_CH 64

__global__ __launch_bounds__(256) void pool_kernel(
    const unsigned short* __restrict__ Z, const int* __restrict__ batch,
    const float* __restrict__ ab, float* __restrict__ out) {
  int tid = blockIdx.x * blockDim.x + threadIdx.x;
  int w = tid >> 6, lane = tid & 63;
  int v0 = w * POOL_CH;
  if (v0 >= N_NODES) return;
  int v1 = min(N_NODES, v0 + POOL_CH);
  float a = ab[lane], b = ab[64 + lane];
  float acc = 0.f;
  int cur = batch[v0];
  for (int v = v0; v < v1; ++v) {
    int bg = batch[v];
    if (bg != cur) {
      atomicAdd(&out[(size_t)cur * HID + lane], acc);
      acc = 0.f;
      cur = bg;
    }
    acc = fmaf(bf1_unpack(Z[(size_t)v * HID + lane]), a, acc + b);
  }
  atomicAdd(&out[(size_t)cur * HID + lane], acc);
}

// ---------------- launch ----------------

extern "C" void kernel_launch(void* const* d_in, const int* in_sizes, int n_in,
                              void* d_out, int out_size, void* d_ws, size_t ws_size,
                              hipStream_t stream) {
  const float* x    = (const float*)d_in[0];
  const int* src    = (const int*)d_in[1];
  const int* dst    = (const int*)d_in[2];
  const int* batch  = (const int*)d_in[3];
  const float* W[4]  = {(const float*)d_in[4], (const float*)d_in[8],
                        (const float*)d_in[12], (const float*)d_in[16]};
  const float* b[4]  = {(const float*)d_in[5], (const float*)d_in[9],
                        (const float*)d_in[13], (const float*)d_in[17]};
  const float* g[4]  = {(const float*)d_in[6], (const float*)d_in[10],
                        (const float*)d_in[14], (const float*)d_in[18]};
  const float* be[4] = {(const float*)d_in[7], (const float*)d_in[11],
                        (const float*)d_in[15], (const float*)d_in[19]};

  char* wsb = (char*)d_ws;
  size_t off = 0;
  auto alloc = [&](size_t bytes) -> void* {
    void* p = wsb + off;
    off += (bytes + 255) & ~(size_t)255;
    return p;
  };
  // zeroed region (one memset)
  int*   binCur = (int*)  alloc((size_t)NBIN * 4);
  float* c0     = (float*)alloc(64 * 4);
  float* stats  = (float*)alloc((size_t)4 * NSLICE * 128 * 4);
  size_t zero_bytes = off;
  // non-zeroed
  float* Ssum   = (float*)alloc((size_t)N_NODES * 4);
  int2*  rowSE  = (int2*) alloc((size_t)N_NODES * 8);
  int*   perm   = (int*)  alloc((size_t)N_NODES * 4);
  float* dinv   = (float*)alloc((size_t)(N_NODES + 1) * 4);
  unsigned* staging = (unsigned*)alloc((size_t)NBIN * BCAP * 4);
  int*   csr    = (int*)  alloc((size_t)NBIN * CSRCAP * 4);
  unsigned short* Hb  = (unsigned short*)alloc((size_t)(N_NODES + 1) * HID * 2);
  unsigned short* Zb  = (unsigned short*)alloc((size_t)N_NODES * HID * 2);
  unsigned short* Wsw = (unsigned short*)alloc((size_t)HID * HID * 2);
  float* cv     = (float*)alloc(64 * 4);
  float* ab     = (float*)alloc(128 * 4);

  hipMemsetAsync(d_ws, 0, zero_bytes, stream);
  hipMemsetAsync(d_out, 0, (size_t)out_size * 4, stream);

  bin_kernel<<<BIN_BLOCKS, 256, 0, stream>>>(src, dst, binCur, staging);
  sort_kernel<<<NBIN, 256, 0, stream>>>(staging, binCur, dinv, rowSE, perm, csr);
  ssum_kernel<<<(N_NODES + 255) / 256, 256, 0, stream>>>(csr, rowSE, perm, dinv, Ssum);

  int gemmBlocks = (N_NODES + 64) / 64;   // covers sentinel row N_NODES
  int posPerAggBlock = AGG_WAVES * 4 * AGG_NPN;
  int aggBlocks = (N_NODES + posPerAggBlock - 1) / posPerAggBlock;

  // layer 1 (K=75, c=0)
  gemm1_kernel<<<gemmBlocks, 256, 0, stream>>>(x, W[0], dinv, Hb);
  agg_kernel<<<aggBlocks, 256, 0, stream>>>(Hb, csr, rowSE, perm, Ssum, dinv, c0, b[0],
                                            Zb, stats);
  prep_kernel<<<1, 256, 0, stream>>>(stats, g[0], be[0], W[1], Wsw, cv, ab, 1);

  // layers 2..4
  for (int l = 1; l < 4; ++l) {
    gemmB_kernel<<<gemmBlocks, 256, 0, stream>>>(Zb, Wsw, dinv, Hb);
    agg_kernel<<<aggBlocks, 256, 0, stream>>>(Hb, csr, rowSE, perm, Ssum, dinv, cv, b[l],
                                              Zb, stats + (size_t)l * NSLICE * 128);
    prep_kernel<<<1, 256, 0, stream>>>(stats + (size_t)l * NSLICE * 128, g[l], be[l],
                                       (l < 3) ? W[l + 1] : nullptr, Wsw, cv, ab,
                                       (l < 3) ? 1 : 0);
  }

  int poolBlocks = (N_NODES + 4 * POOL_CH - 1) / (4 * POOL_CH);
  pool_kernel<<<poolBlocks, 256, 0, stream>>>(Zb, batch, ab, (float*)d_out);
}